// Round 1
// 774.326 us; speedup vs baseline: 1.0227x; 1.0227x over previous
//
#include <hip/hip_runtime.h>

#define NUM_VOXELS     1000000
#define N_POINTS       1500000
#define TOTAL_PROP_PTS 1000000
#define NUM_PROPOSALS  2048
#define IN_CH          134
#define M_OUT          16

// ---------------------------------------------------------------------------
// K1: feats = relu(voxel_feats @ W)
//   A: [NUM_VOXELS][134] f32 (row 536 B), W: [134][16] f32, feats: [NUM_VOXELS][16]
//
// v2 changes vs previous session (theory: K1 was latency-bound, not BW-bound):
//  - K-chunk 64 -> 32 cols: LDS/block 66.5 KB -> 33.8 KB -> 4 blocks/CU
//    (16 waves/CU instead of 8).
//  - Register double-buffer: 16 float2 staged per chunk, FULLY unrolled
//    (16 loads in flight vs 4 with the old "#pragma unroll 4"), and the
//    next chunk's global loads are issued BEFORE the compute phase of the
//    current chunk, so ~900cy HBM latency hides under ~1200cy of FMA.
//  - K-tail (cols 128..133) read per-lane as 3x float2 at kernel start,
//    consumed from registers at the end (no LDS, latency fully hidden).
//
// LDS banking (pad 33): compute read chunk[lane*33+kk] -> bank (lane+kk)%32,
// 2-way = free. Staging ds_write_b64: each quarter-wave covers all 32 banks
// once -> 4 dwords/bank = minimum. No __syncthreads (LDS wave-private).
// ---------------------------------------------------------------------------
__global__ __launch_bounds__(256, 4) void k_gemm_relu(
    const float* __restrict__ A, const float* __restrict__ W,
    float* __restrict__ feats)
{
    __shared__ float lds[4][64 * 33];
    const int wave = threadIdx.x >> 6;
    const int lane = threadIdx.x & 63;
    const int v0   = blockIdx.x * 256 + wave * 64;   // wave's first voxel
    if (v0 >= NUM_VOXELS) return;                    // NUM_VOXELS % 64 == 0

    float* chunk = lds[wave];

    // ---- K-tail: cols 128..133 of my own voxel row, 3x float2 (8B aligned:
    //      (v*134+128) is even). Issued first so latency hides under staging.
    const float* myrow = A + (size_t)(v0 + lane) * IN_CH;
    const float2 tl0 = *(const float2*)(myrow + 128);
    const float2 tl1 = *(const float2*)(myrow + 130);
    const float2 tl2 = *(const float2*)(myrow + 132);

    // ---- staging geometry: iter j stages rows 4j..4j+3, 32 floats each.
    //      lane -> row offset srow = lane>>4 (0..3), col pair scol = (lane&15)*2.
    //      Each 16-lane quarter reads 128 contiguous bytes -> coalesced.
    const int srow = lane >> 4;
    const int scol = (lane & 15) * 2;
    const float* sbase = A + (size_t)(v0 + srow) * IN_CH + scol;

    float2 buf[16];
#pragma unroll
    for (int j = 0; j < 16; ++j)                     // prefetch chunk 0 (kc=0)
        buf[j] = *(const float2*)(sbase + (size_t)j * 4 * IN_CH);

    float acc[M_OUT];
#pragma unroll
    for (int c = 0; c < M_OUT; ++c) acc[c] = 0.f;

#pragma unroll
    for (int cidx = 0; cidx < 4; ++cidx) {
        const int kc = cidx * 32;

        // drain staged regs into LDS (waits vmcnt on buf implicitly)
#pragma unroll
        for (int j = 0; j < 16; ++j) {
            const int row = j * 4 + srow;
            *(float2*)&chunk[row * 33 + scol] = buf[j];
        }

        // issue NEXT chunk's 16 loads now -> in flight during compute below
        if (cidx < 3) {
            const float* nb = sbase + kc + 32;
#pragma unroll
            for (int j = 0; j < 16; ++j)
                buf[j] = *(const float2*)(nb + (size_t)j * 4 * IN_CH);
        }

        // compute: 32 kk x (1 bank-free ds_read_b32 + 16 FMA w/ scalar W)
        const float* wbase = W + kc * M_OUT;
#pragma unroll
        for (int kk = 0; kk < 32; ++kk) {
            const float a = chunk[lane * 33 + kk];
            const float* wr = wbase + kk * M_OUT;
#pragma unroll
            for (int c = 0; c < M_OUT; ++c) acc[c] = fmaf(a, wr[c], acc[c]);
        }
    }

    // ---- K-tail compute from registers (cols 128..133)
    {
        const float* wr = W + 128 * M_OUT;
#pragma unroll
        for (int c = 0; c < M_OUT; ++c) {
            float v = fmaf(tl0.x, wr[0 * M_OUT + c], acc[c]);
            v = fmaf(tl0.y, wr[1 * M_OUT + c], v);
            v = fmaf(tl1.x, wr[2 * M_OUT + c], v);
            v = fmaf(tl1.y, wr[3 * M_OUT + c], v);
            v = fmaf(tl2.x, wr[4 * M_OUT + c], v);
            acc[c] = fmaf(tl2.y, wr[5 * M_OUT + c], v);
        }
    }

    // relu + store 64 B per voxel
    float4* orow = (float4*)(feats + (size_t)(v0 + lane) * M_OUT);
#pragma unroll
    for (int q = 0; q < 4; ++q) {
        float4 o;
        o.x = fmaxf(acc[q * 4 + 0], 0.f);
        o.y = fmaxf(acc[q * 4 + 1], 0.f);
        o.z = fmaxf(acc[q * 4 + 2], 0.f);
        o.w = fmaxf(acc[q * 4 + 3], 0.f);
        orow[q] = o;
    }
}

// ---------------------------------------------------------------------------
// K2: per-proposal segmented mean + batchId + objectness.
// One block per proposal, thread-per-point. v2: software-pipeline the
// dependent chain -- iteration i+1's prop_idx->p2v loads are issued before
// iteration i's feats gathers, so the ~2-deep index chain overlaps the
// 64 B feats gather instead of serializing with it. prop_idx read as int2
// (8 B coalesced). out layout (f32): [P*16 means][P batchId][P ones]
// ---------------------------------------------------------------------------
__global__ __launch_bounds__(256) void k_propmean(
    const float* __restrict__ feats,
    const int*   __restrict__ p2v,       // [N_POINTS]
    const int*   __restrict__ prop_idx,  // [T][2], col 1 = point index
    const int*   __restrict__ offsets,   // [P+1]
    const int*   __restrict__ locs,      // [N_POINTS][4], col 0 = batch id
    float*       __restrict__ out)
{
    const int s   = blockIdx.x;
    const int tid = threadIdx.x;
    const int t0  = offsets[s];
    const int t1  = offsets[s + 1];
    const int2* pidx2 = (const int2*)prop_idx;

    float acc[M_OUT];
#pragma unroll
    for (int c = 0; c < M_OUT; ++c) acc[c] = 0.f;

    int t = t0 + tid;
    bool have = (t < t1);
    int v = 0;
    if (have) v = p2v[pidx2[t].y];       // head of the pipeline

    while (have) {
        // issue next iteration's index chain BEFORE the feats gather
        const int  tn     = t + 256;
        const bool have_n = (tn < t1);
        int vn = 0;
        if (have_n) vn = p2v[pidx2[tn].y];

        const float4* fp = (const float4*)(feats + (size_t)v * M_OUT);
        const float4 f0 = fp[0], f1 = fp[1], f2 = fp[2], f3 = fp[3];
        acc[0]  += f0.x; acc[1]  += f0.y; acc[2]  += f0.z; acc[3]  += f0.w;
        acc[4]  += f1.x; acc[5]  += f1.y; acc[6]  += f1.z; acc[7]  += f1.w;
        acc[8]  += f2.x; acc[9]  += f2.y; acc[10] += f2.z; acc[11] += f2.w;
        acc[12] += f3.x; acc[13] += f3.y; acc[14] += f3.z; acc[15] += f3.w;

        v = vn; t = tn; have = have_n;
    }

    // wave-level reduction (width 64)
#pragma unroll
    for (int c = 0; c < M_OUT; ++c) {
#pragma unroll
        for (int off = 32; off > 0; off >>= 1)
            acc[c] += __shfl_down(acc[c], off, 64);
    }

    __shared__ float red[4][M_OUT];
    const int lane = tid & 63, wv = tid >> 6;
    if (lane == 0) {
#pragma unroll
        for (int c = 0; c < M_OUT; ++c) red[wv][c] = acc[c];
    }
    __syncthreads();

    if (tid < M_OUT) {
        const float sum = red[0][tid] + red[1][tid] + red[2][tid] + red[3][tid];
        const float cnt = (float)(t1 - t0);
        out[s * M_OUT + tid] = sum / fmaxf(cnt, 1.f);
    }
    if (tid == 0) {
        // offsets[s] < T for s < P, so this index is always valid
        const int p = prop_idx[2 * t0 + 1];
        out[NUM_PROPOSALS * M_OUT + s]                 = (float)locs[4 * p];
        out[NUM_PROPOSALS * M_OUT + NUM_PROPOSALS + s] = 1.0f;
    }
}

// ---------------------------------------------------------------------------
// NOTE (timing model, r0): dur_us includes ~330 us of harness ws-poison fill
// (fillBufferAligned, 2.14 GB WRITE, one per timed iteration at dispatch
// id % 10 == 0). Kernel-attributable time is dur_us - ~340. Rooflines:
// K1 ~95 us (600 MB stream), K2 ~30-60 us (random 128 B gathers).
// ---------------------------------------------------------------------------
extern "C" void kernel_launch(void* const* d_in, const int* in_sizes, int n_in,
                              void* d_out, int out_size, void* d_ws, size_t ws_size,
                              hipStream_t stream)
{
    const float* A    = (const float*)d_in[0];   // voxel_feats [1M][134]
    const float* W    = (const float*)d_in[1];   // [134][16]
    const int*   p2v  = (const int*)  d_in[2];   // [1.5M]
    const int*   pidx = (const int*)  d_in[3];   // [1M][2]
    const int*   offs = (const int*)  d_in[4];   // [2049]
    const int*   locs = (const int*)  d_in[5];   // [1.5M][4]
    float*       out  = (float*)      d_out;     // 36864 f32
    float*       feats = (float*)     d_ws;      // 64 MB scratch

    k_gemm_relu<<<(NUM_VOXELS + 255) / 256, 256, 0, stream>>>(A, W, feats);
    k_propmean<<<NUM_PROPOSALS, 256, 0, stream>>>(feats, p2v, pidx, offs, locs, out);
}